// Round 15
// baseline (125.304 us; speedup 1.0000x reference)
//
#include <hip/hip_runtime.h>
#include <hip/hip_bf16.h>
#include <math.h>

#define LN_EPS 1e-5f

typedef float f32x4 __attribute__((ext_vector_type(4)));
typedef short s16x8 __attribute__((ext_vector_type(8)));

__device__ __forceinline__ unsigned short f2bf(float f) {
  return __builtin_bit_cast(unsigned short, __float2bfloat16(f));  // RNE
}
__device__ __forceinline__ float bf_lo(unsigned int u) { return __uint_as_float(u << 16); }
__device__ __forceinline__ float bf_hi(unsigned int u) { return __uint_as_float(u & 0xFFFF0000u); }

// Buckets are 64 rows. Slot region for (bucket bk, xcd x) = brec[(bk*8+x)*CAP ...).
// lrow (6 bits) packed into rec.x bits 20-25 (col < 2^17).

// ================= fat build kernel: scatter | gemm by blockIdx =================
// Blocks [0,SB): single-pass bucket scatter, 8192 edges/block (16/thread held in
//   REGISTERS — launch_bounds(512,2) caps waves not VGPRs, preventing the r14
//   spill of the edge arrays to scratch). LDS hist atomic captures block-local
//   rank; ONE ticket atomic per nonzero bin per block (~400K total); place into
//   per-(bucket,xcd) fixed-CAP slots. xcd=blockIdx&7 -> writers share an XCD.
// Blocks [SB,SB+GEMMB): h = feats @ W via 16x16x32 bf16 MFMA, packed-split store
//   hu[r*64+l] = pack(bf16(h[r][l]), bf16(h[r][l+64])).
__global__ __launch_bounds__(512, 2) void k_build(const unsigned int* __restrict__ idx,
                                                  const float* __restrict__ vals,
                                                  const float* __restrict__ feats,
                                                  const float* __restrict__ W,
                                                  int E, int N, int CAP, int SB,
                                                  int* __restrict__ scnt,
                                                  int2* __restrict__ brec,
                                                  unsigned int* __restrict__ hu) {
  __shared__ __align__(16) char smem[34816];
  int t = threadIdx.x;
  if ((int)blockIdx.x < SB) {
    // ---------------- scatter path (2048 bins of 64 rows; 8192 edges/block) --------
    int* lcnt = (int*)smem;    // [2048]
    int* lbase = lcnt + 2048;  // [2048]
    int* sflag = lbase + 2048;
    if (t == 0) *sflag = 0;
    for (int i = t; i < 2048; i += 512) lcnt[i] = 0;
    __syncthreads();
    {  // inline dtype detect: int64 iff high u32 of first 4096 qwords all zero
      int nchk = E < 4096 ? E : 4096;
      unsigned int orv = 0u;
      for (int i = t; i < nchk; i += 512) orv |= idx[2 * i + 1];
      if (orv) atomicOr(sflag, 1);
    }
    __syncthreads();
    bool is64 = (*sflag == 0);
    int xcd = blockIdx.x & 7;
    int packed[16], vb[16], meta[16];  // static-indexed (full unroll) -> registers
#pragma unroll
    for (int c = 0; c < 2; ++c) {
      int e0 = blockIdx.x * 8192 + c * 4096 + t * 8;
      int rows[8], cols[8];
      float vv[8];
      if (e0 + 7 < E) {
        if (is64) {
#pragma unroll
          for (int q = 0; q < 4; ++q) {
            int4 a = *(const int4*)(idx + 2 * e0 + 4 * q);
            rows[2 * q] = a.x; rows[2 * q + 1] = a.z;
            int4 cc = *(const int4*)(idx + 2 * E + 2 * e0 + 4 * q);
            cols[2 * q] = cc.x; cols[2 * q + 1] = cc.z;
          }
        } else {
          const int* p = (const int*)idx;
#pragma unroll
          for (int q = 0; q < 2; ++q) {
            int4 a = *(const int4*)(p + e0 + 4 * q);
            rows[4 * q] = a.x; rows[4 * q + 1] = a.y; rows[4 * q + 2] = a.z; rows[4 * q + 3] = a.w;
            int4 cc = *(const int4*)(p + E + e0 + 4 * q);
            cols[4 * q] = cc.x; cols[4 * q + 1] = cc.y; cols[4 * q + 2] = cc.z; cols[4 * q + 3] = cc.w;
          }
        }
        float4 va = *(const float4*)(vals + e0);
        float4 vbv = *(const float4*)(vals + e0 + 4);
        vv[0] = va.x; vv[1] = va.y; vv[2] = va.z; vv[3] = va.w;
        vv[4] = vbv.x; vv[5] = vbv.y; vv[6] = vbv.z; vv[7] = vbv.w;
      } else {
#pragma unroll
        for (int q = 0; q < 8; ++q) {
          int e = e0 + q;
          rows[q] = -1;
          if (e < E) {
            rows[q] = is64 ? (int)idx[2 * e] : ((const int*)idx)[e];
            cols[q] = is64 ? (int)idx[2 * E + 2 * e] : ((const int*)idx)[E + e];
            vv[q] = vals[e];
          }
        }
      }
#pragma unroll
      for (int q = 0; q < 8; ++q) {
        int j = c * 8 + q;
        if (rows[q] >= 0) {
          int bk = rows[q] >> 6;
          int lrk = atomicAdd(&lcnt[bk], 1);  // block-local rank (< 8192)
          meta[j] = (bk << 13) | lrk;         // bk < 2048 (11b), lrk 13b
          packed[j] = cols[q] | ((rows[q] & 63) << 20);
          vb[j] = __float_as_int(vv[q]);
        } else {
          meta[j] = -1;
        }
      }
    }
    __syncthreads();
    for (int i = t; i < 2048; i += 512) {
      int c = lcnt[i];
      lbase[i] = c ? atomicAdd(&scnt[(i * 8 + xcd) * 16], c) : 0;  // one ticket/bin
    }
    __syncthreads();
#pragma unroll
    for (int j = 0; j < 16; ++j) {
      if (meta[j] >= 0) {
        int bk = meta[j] >> 13;
        int p = lbase[bk] + (meta[j] & 8191);
        if (p < CAP)  // overflow guard (prob ~1e-10 overall): drop, never corrupt
          brec[(size_t)(bk * 8 + xcd) * CAP + p] = make_int2(packed[j], vb[j]);
      }
    }
  } else {
    // ---------------- gemm path (8 waves x 16 rows = 128 rows/block) ----------------
    unsigned short (*Wt)[136] = (unsigned short(*)[136])smem;  // 128*136*2 = 34816B
    for (int i = t; i < 16384; i += 512) {
      int k = i & 127, c = i >> 7;
      Wt[c][k] = f2bf(W[k * 128 + c]);
    }
    __syncthreads();
    int wid = t >> 6, lane = t & 63;
    int rlo = lane & 15, khi = lane >> 4;
    int row0 = (blockIdx.x - SB) * 128 + wid * 16;
    f32x4 zero = {0.f, 0.f, 0.f, 0.f};
    f32x4 acc[8];
#pragma unroll
    for (int n = 0; n < 8; ++n) acc[n] = zero;
#pragma unroll
    for (int kb = 0; kb < 4; ++kb) {
      int k0 = kb * 32 + khi * 8;
      int r = row0 + rlo;
      if (r > N - 1) r = N - 1;
      const float* p = feats + (size_t)r * 128 + k0;
      f32x4 a0 = *(const f32x4*)p;
      f32x4 a1 = *(const f32x4*)(p + 4);
      s16x8 af;
#pragma unroll
      for (int j = 0; j < 4; ++j) af[j] = (short)f2bf(a0[j]);
#pragma unroll
      for (int j = 0; j < 4; ++j) af[4 + j] = (short)f2bf(a1[j]);
#pragma unroll
      for (int n = 0; n < 8; ++n) {
        s16x8 bfr = *(const s16x8*)&Wt[n * 16 + rlo][k0];
        acc[n] = __builtin_amdgcn_mfma_f32_16x16x32_bf16(af, bfr, acc[n], 0, 0, 0);
      }
    }
    // D layout: col = lane&15 (=rlo), row = khi*4 + reg
#pragma unroll
    for (int n = 0; n < 4; ++n)
#pragma unroll
      for (int reg = 0; reg < 4; ++reg) {
        int r = row0 + khi * 4 + reg;
        if (r < N) {
          unsigned int lo = f2bf(acc[n][reg]);
          unsigned int hi = f2bf(acc[n + 4][reg]);
          hu[(size_t)r * 64 + n * 16 + rlo] = lo | (hi << 16);
        }
      }
  }
}

// ===== fused localize + SpMM + bias + ELU + LayerNorm; one block per 64-row bucket =====
// Stage slot records to registers (1 global read); LDS-atomic histogram captures
// within-row rank; single-wave shfl scan; scatter into LDS sorted order WITH lrow
// stripped (position encodes row); wave w register-accumulates rows [w*8, w*8+8)
// from srec (col hoisted to SGPR -> saddr gathers, voffset lane*4).
#define SCAPMAX 2048  // 8*CAP must be <= this
#define LRPT 4
__global__ __launch_bounds__(512, 8) void k_spmmL(const unsigned int* __restrict__ hu,
                                                  const int* __restrict__ scnt, int CAP,
                                                  const int2* __restrict__ brec,
                                                  const float* __restrict__ bias,
                                                  const float* __restrict__ gamma,
                                                  const float* __restrict__ beta,
                                                  float* __restrict__ out, int N) {
  __shared__ int2 srec[SCAPMAX];
  __shared__ int cnt[64], base[64], prefs[9];
  int b = blockIdx.x, t = threadIdx.x;
  int wid = __builtin_amdgcn_readfirstlane(t >> 6);
  int lane = t & 63;
  if (t < 64) cnt[t] = 0;
  if (t == 0) {
    int s = 0;
#pragma unroll
    for (int x = 0; x < 8; ++x) { prefs[x] = s; s += min(scnt[(b * 8 + x) * 16], CAP); }
    prefs[8] = s;
  }
  // hoist epilogue constants
  float b0 = bias[lane], b1 = bias[lane + 64];
  float g0 = gamma[lane], g1 = gamma[lane + 64];
  float be0 = beta[lane], be1 = beta[lane + 64];
  __syncthreads();
  int pr[9];
#pragma unroll
  for (int x = 0; x < 9; ++x) pr[x] = prefs[x];
  int M = pr[8];

  // stage + histogram (rank captured by the same atomic)
  int2 myrec[LRPT];
  int lr[LRPT], lrk[LRPT];
#pragma unroll
  for (int q = 0; q < LRPT; ++q) {
    int i = q * 512 + t;
    lr[q] = -1;
    if (i < M) {
      int x = 0;
#pragma unroll
      for (int xx = 1; xx < 8; ++xx) x += (i >= pr[xx]) ? 1 : 0;
      myrec[q] = brec[(size_t)(b * 8 + x) * CAP + (i - pr[x])];
      lr[q] = (unsigned)myrec[q].x >> 20;
      lrk[q] = atomicAdd(&cnt[lr[q]], 1);
    }
  }
  __syncthreads();
  // single-wave shfl scan over 64 bins -> exclusive base
  if (t < 64) {
    int c = cnt[t];
    int inc = c;
#pragma unroll
    for (int d = 1; d < 64; d <<= 1) {
      int y = __shfl_up(inc, d);
      if (t >= d) inc += y;
    }
    base[t] = inc - c;
  }
  __syncthreads();
#pragma unroll
  for (int q = 0; q < LRPT; ++q)
    if (lr[q] >= 0)
      srec[base[lr[q]] + lrk[q]] = make_int2(myrec[q].x & 0xFFFFF, myrec[q].y);  // col only
  __syncthreads();

  // per-wave: 8 rows, register accumulate from LDS-sorted records
  for (int j = 0; j < 8; ++j) {
    int lrow = wid * 8 + j;
    int r = b * 64 + lrow;
    if (r >= N) break;
    int i = base[lrow], end = i + cnt[lrow];
    float a0 = 0.f, a1 = 0.f;
    for (; i + 8 <= end; i += 8) {
      unsigned int u[8];
      float v[8];
#pragma unroll
      for (int q = 0; q < 8; ++q) {
        int2 e = srec[i + q];
        int col = __builtin_amdgcn_readfirstlane(e.x);
        u[q] = hu[(size_t)col * 64 + lane];
        v[q] = __int_as_float(e.y);
      }
#pragma unroll
      for (int q = 0; q < 8; ++q) {
        a0 = fmaf(v[q], bf_lo(u[q]), a0);
        a1 = fmaf(v[q], bf_hi(u[q]), a1);
      }
    }
    for (; i + 4 <= end; i += 4) {
      unsigned int u[4];
      float v[4];
#pragma unroll
      for (int q = 0; q < 4; ++q) {
        int2 e = srec[i + q];
        int col = __builtin_amdgcn_readfirstlane(e.x);
        u[q] = hu[(size_t)col * 64 + lane];
        v[q] = __int_as_float(e.y);
      }
#pragma unroll
      for (int q = 0; q < 4; ++q) {
        a0 = fmaf(v[q], bf_lo(u[q]), a0);
        a1 = fmaf(v[q], bf_hi(u[q]), a1);
      }
    }
    for (; i < end; ++i) {
      int2 e = srec[i];
      int col = __builtin_amdgcn_readfirstlane(e.x);
      unsigned int u = hu[(size_t)col * 64 + lane];
      float v = __int_as_float(e.y);
      a0 = fmaf(v, bf_lo(u), a0);
      a1 = fmaf(v, bf_hi(u), a1);
    }

    // dims: a0 -> lane, a1 -> lane+64 (packed-split h layout)
    float x0 = a0 + b0, x1 = a1 + b1;
    x0 = x0 > 0.f ? x0 : __expf(x0) - 1.f;
    x1 = x1 > 0.f ? x1 : __expf(x1) - 1.f;
    float s = x0 + x1;
#pragma unroll
    for (int d = 1; d < 64; d <<= 1) s += __shfl_xor(s, d);
    float mu = s * (1.f / 128.f);
    float d0 = x0 - mu, d1 = x1 - mu;
    float q2 = d0 * d0 + d1 * d1;
#pragma unroll
    for (int d = 1; d < 64; d <<= 1) q2 += __shfl_xor(q2, d);
    float rstd = rsqrtf(q2 * (1.f / 128.f) + LN_EPS);
    __builtin_nontemporal_store(d0 * rstd * g0 + be0, out + (size_t)r * 128 + lane);
    __builtin_nontemporal_store(d1 * rstd * g1 + be1, out + (size_t)r * 128 + 64 + lane);
  }
}

extern "C" void kernel_launch(void* const* d_in, const int* in_sizes, int n_in,
                              void* d_out, int out_size, void* d_ws, size_t ws_size,
                              hipStream_t stream) {
  const float* feats = (const float*)d_in[0];
  const unsigned int* idx = (const unsigned int*)d_in[1];
  const float* vals = (const float*)d_in[2];
  const float* W = (const float*)d_in[3];
  const float* bias = (const float*)d_in[4];
  const float* gamma = (const float*)d_in[5];
  const float* beta = (const float*)d_in[6];
  float* out = (float*)d_out;
  int N = in_sizes[0] / 128;
  int E = in_sizes[2];
  (void)n_in; (void)out_size; (void)ws_size;

  int NBUK = (N + 63) >> 6;   // 1563 for N=100000 (must be <=2048 for LDS hist)
  int NV = NBUK * 8;          // per-(bucket,xcd) slots
  int mean = (E + NV - 1) / NV;                 // ~128
  int sig = (int)ceilf(sqrtf((float)mean));     // Poisson sigma
  int CAP = ((mean + 8 * sig + 15) / 16) * 16;  // mean + 8 sigma
  if (8 * CAP > SCAPMAX) CAP = SCAPMAX / 8;     // LDS capacity clamp

  char* ws = (char*)d_ws;
  size_t off = 0;
  auto alloc = [&](size_t bytes) {
    char* p = ws + off;
    off += (bytes + 255) & ~(size_t)255;
    return p;
  };
  unsigned int* hu = (unsigned int*)alloc((size_t)N * 64 * 4);  // 25.6MB
  int* scnt = (int*)alloc((size_t)NV * 64);                     // padded counters, 0.8MB
  int2* brec = (int2*)alloc((size_t)NV * CAP * 8);              // ~22.4MB slots

  hipMemsetAsync(scnt, 0, (size_t)NV * 64, stream);

  int SB = (E + 8191) / 8192;    // scatter blocks (8192 edges each)
  int GEMMB = (N + 127) / 128;   // gemm blocks
  k_build<<<SB + GEMMB, 512, 0, stream>>>(idx, vals, feats, W, E, N, CAP, SB, scnt, brec, hu);
  k_spmmL<<<NBUK, 512, 0, stream>>>(hu, scnt, CAP, brec, bias, gamma, beta, out, N);
}

// Round 16
// 115.038 us; speedup vs baseline: 1.0892x; 1.0892x over previous
//
#include <hip/hip_runtime.h>
#include <hip/hip_bf16.h>
#include <math.h>

#define LN_EPS 1e-5f

typedef float f32x4 __attribute__((ext_vector_type(4)));
typedef short s16x8 __attribute__((ext_vector_type(8)));

__device__ __forceinline__ unsigned short f2bf(float f) {
  return __builtin_bit_cast(unsigned short, __float2bfloat16(f));  // RNE
}
__device__ __forceinline__ float bf_lo(unsigned int u) { return __uint_as_float(u << 16); }
__device__ __forceinline__ float bf_hi(unsigned int u) { return __uint_as_float(u & 0xFFFF0000u); }

// Buckets are 64 rows. Slot region for (bucket bk, xcd x) = brec[(bk*8+x)*CAP ...).
// lrow (6 bits) packed into rec.x bits 20-25 (col < 2^17).

// ================= fat build kernel: scatter | gemm by blockIdx =================
// Blocks [0,SB): single-pass bucket scatter, 16384 edges/block (32/thread). LDS
//   hist atomic captures block-local rank; ONE ticket atomic per nonzero bin per
//   block (~200K total); place into per-(bucket,xcd) fixed-CAP slots.
//   xcd=blockIdx&7 -> slot writers share an XCD -> L2 line merge.
//   [r15 lesson: do NOT add launch_bounds min-waves or shrink the batch — both
//    regressed ~9µs. This exact config measured 116.4µs total.]
// Blocks [SB,SB+GEMMB): h = feats @ W via 16x16x32 bf16 MFMA, packed-split store
//   hu[r*64+l] = pack(bf16(h[r][l]), bf16(h[r][l+64])).
__global__ __launch_bounds__(512) void k_build(const unsigned int* __restrict__ idx,
                                               const float* __restrict__ vals,
                                               const float* __restrict__ feats,
                                               const float* __restrict__ W,
                                               int E, int N, int CAP, int SB,
                                               int* __restrict__ scnt,
                                               int2* __restrict__ brec,
                                               unsigned int* __restrict__ hu) {
  __shared__ __align__(16) char smem[34816];
  int t = threadIdx.x;
  if ((int)blockIdx.x < SB) {
    // ---------------- scatter path (2048 bins of 64 rows; 16384 edges/block) --------
    int* lcnt = (int*)smem;    // [2048]
    int* lbase = lcnt + 2048;  // [2048]
    int* sflag = lbase + 2048;
    if (t == 0) *sflag = 0;
    for (int i = t; i < 2048; i += 512) lcnt[i] = 0;
    __syncthreads();
    {  // inline dtype detect: int64 iff high u32 of first 4096 qwords all zero
      int nchk = E < 4096 ? E : 4096;
      unsigned int orv = 0u;
      for (int i = t; i < nchk; i += 512) orv |= idx[2 * i + 1];
      if (orv) atomicOr(sflag, 1);
    }
    __syncthreads();
    bool is64 = (*sflag == 0);
    int xcd = blockIdx.x & 7;
    int packed[32], vb[32], meta[32];  // static-indexed (full unroll)
#pragma unroll
    for (int c = 0; c < 4; ++c) {
      int e0 = blockIdx.x * 16384 + c * 4096 + t * 8;
      int rows[8], cols[8];
      float vv[8];
      if (e0 + 7 < E) {
        if (is64) {
#pragma unroll
          for (int q = 0; q < 4; ++q) {
            int4 a = *(const int4*)(idx + 2 * e0 + 4 * q);
            rows[2 * q] = a.x; rows[2 * q + 1] = a.z;
            int4 cc = *(const int4*)(idx + 2 * E + 2 * e0 + 4 * q);
            cols[2 * q] = cc.x; cols[2 * q + 1] = cc.z;
          }
        } else {
          const int* p = (const int*)idx;
#pragma unroll
          for (int q = 0; q < 2; ++q) {
            int4 a = *(const int4*)(p + e0 + 4 * q);
            rows[4 * q] = a.x; rows[4 * q + 1] = a.y; rows[4 * q + 2] = a.z; rows[4 * q + 3] = a.w;
            int4 cc = *(const int4*)(p + E + e0 + 4 * q);
            cols[4 * q] = cc.x; cols[4 * q + 1] = cc.y; cols[4 * q + 2] = cc.z; cols[4 * q + 3] = cc.w;
          }
        }
        float4 va = *(const float4*)(vals + e0);
        float4 vbv = *(const float4*)(vals + e0 + 4);
        vv[0] = va.x; vv[1] = va.y; vv[2] = va.z; vv[3] = va.w;
        vv[4] = vbv.x; vv[5] = vbv.y; vv[6] = vbv.z; vv[7] = vbv.w;
      } else {
#pragma unroll
        for (int q = 0; q < 8; ++q) {
          int e = e0 + q;
          rows[q] = -1;
          if (e < E) {
            rows[q] = is64 ? (int)idx[2 * e] : ((const int*)idx)[e];
            cols[q] = is64 ? (int)idx[2 * E + 2 * e] : ((const int*)idx)[E + e];
            vv[q] = vals[e];
          }
        }
      }
#pragma unroll
      for (int q = 0; q < 8; ++q) {
        int j = c * 8 + q;
        if (rows[q] >= 0) {
          int bk = rows[q] >> 6;
          int lrk = atomicAdd(&lcnt[bk], 1);  // block-local rank
          meta[j] = (bk << 14) | lrk;         // bk < 2048 (11b), lrk < 16384 (14b)
          packed[j] = cols[q] | ((rows[q] & 63) << 20);
          vb[j] = __float_as_int(vv[q]);
        } else {
          meta[j] = -1;
        }
      }
    }
    __syncthreads();
    for (int i = t; i < 2048; i += 512) {
      int c = lcnt[i];
      lbase[i] = c ? atomicAdd(&scnt[(i * 8 + xcd) * 16], c) : 0;  // one ticket/bin
    }
    __syncthreads();
#pragma unroll
    for (int j = 0; j < 32; ++j) {
      if (meta[j] >= 0) {
        int bk = meta[j] >> 14;
        int p = lbase[bk] + (meta[j] & 16383);
        if (p < CAP)  // overflow guard (prob ~1e-10 overall): drop, never corrupt
          brec[(size_t)(bk * 8 + xcd) * CAP + p] = make_int2(packed[j], vb[j]);
      }
    }
  } else {
    // ---------------- gemm path (8 waves x 16 rows = 128 rows/block) ----------------
    unsigned short (*Wt)[136] = (unsigned short(*)[136])smem;  // 128*136*2 = 34816B
    for (int i = t; i < 16384; i += 512) {
      int k = i & 127, c = i >> 7;
      Wt[c][k] = f2bf(W[k * 128 + c]);
    }
    __syncthreads();
    int wid = t >> 6, lane = t & 63;
    int rlo = lane & 15, khi = lane >> 4;
    int row0 = (blockIdx.x - SB) * 128 + wid * 16;
    f32x4 zero = {0.f, 0.f, 0.f, 0.f};
    f32x4 acc[8];
#pragma unroll
    for (int n = 0; n < 8; ++n) acc[n] = zero;
#pragma unroll
    for (int kb = 0; kb < 4; ++kb) {
      int k0 = kb * 32 + khi * 8;
      int r = row0 + rlo;
      if (r > N - 1) r = N - 1;
      const float* p = feats + (size_t)r * 128 + k0;
      f32x4 a0 = *(const f32x4*)p;
      f32x4 a1 = *(const f32x4*)(p + 4);
      s16x8 af;
#pragma unroll
      for (int j = 0; j < 4; ++j) af[j] = (short)f2bf(a0[j]);
#pragma unroll
      for (int j = 0; j < 4; ++j) af[4 + j] = (short)f2bf(a1[j]);
#pragma unroll
      for (int n = 0; n < 8; ++n) {
        s16x8 bfr = *(const s16x8*)&Wt[n * 16 + rlo][k0];
        acc[n] = __builtin_amdgcn_mfma_f32_16x16x32_bf16(af, bfr, acc[n], 0, 0, 0);
      }
    }
    // D layout: col = lane&15 (=rlo), row = khi*4 + reg
#pragma unroll
    for (int n = 0; n < 4; ++n)
#pragma unroll
      for (int reg = 0; reg < 4; ++reg) {
        int r = row0 + khi * 4 + reg;
        if (r < N) {
          unsigned int lo = f2bf(acc[n][reg]);
          unsigned int hi = f2bf(acc[n + 4][reg]);
          hu[(size_t)r * 64 + n * 16 + rlo] = lo | (hi << 16);
        }
      }
  }
}

// ===== fused localize + SpMM + bias + ELU + LayerNorm; one block per 64-row bucket =====
// Stage slot records to registers (1 global read); LDS-atomic histogram captures
// within-row rank; single-wave shfl scan; scatter into LDS sorted order WITH lrow
// stripped (position encodes row); wave w register-accumulates rows [w*8, w*8+8)
// from srec (col hoisted to SGPR -> saddr gathers, voffset lane*4).
#define SCAPMAX 2048  // 8*CAP must be <= this
#define LRPT 4
__global__ __launch_bounds__(512, 8) void k_spmmL(const unsigned int* __restrict__ hu,
                                                  const int* __restrict__ scnt, int CAP,
                                                  const int2* __restrict__ brec,
                                                  const float* __restrict__ bias,
                                                  const float* __restrict__ gamma,
                                                  const float* __restrict__ beta,
                                                  float* __restrict__ out, int N) {
  __shared__ int2 srec[SCAPMAX];
  __shared__ int cnt[64], base[64], prefs[9];
  int b = blockIdx.x, t = threadIdx.x;
  int wid = __builtin_amdgcn_readfirstlane(t >> 6);
  int lane = t & 63;
  if (t < 64) cnt[t] = 0;
  if (t == 0) {
    int s = 0;
#pragma unroll
    for (int x = 0; x < 8; ++x) { prefs[x] = s; s += min(scnt[(b * 8 + x) * 16], CAP); }
    prefs[8] = s;
  }
  // hoist epilogue constants
  float b0 = bias[lane], b1 = bias[lane + 64];
  float g0 = gamma[lane], g1 = gamma[lane + 64];
  float be0 = beta[lane], be1 = beta[lane + 64];
  __syncthreads();
  int pr[9];
#pragma unroll
  for (int x = 0; x < 9; ++x) pr[x] = prefs[x];
  int M = pr[8];

  // stage + histogram (rank captured by the same atomic)
  int2 myrec[LRPT];
  int lr[LRPT], lrk[LRPT];
#pragma unroll
  for (int q = 0; q < LRPT; ++q) {
    int i = q * 512 + t;
    lr[q] = -1;
    if (i < M) {
      int x = 0;
#pragma unroll
      for (int xx = 1; xx < 8; ++xx) x += (i >= pr[xx]) ? 1 : 0;
      myrec[q] = brec[(size_t)(b * 8 + x) * CAP + (i - pr[x])];
      lr[q] = (unsigned)myrec[q].x >> 20;
      lrk[q] = atomicAdd(&cnt[lr[q]], 1);
    }
  }
  __syncthreads();
  // single-wave shfl scan over 64 bins -> exclusive base
  if (t < 64) {
    int c = cnt[t];
    int inc = c;
#pragma unroll
    for (int d = 1; d < 64; d <<= 1) {
      int y = __shfl_up(inc, d);
      if (t >= d) inc += y;
    }
    base[t] = inc - c;
  }
  __syncthreads();
#pragma unroll
  for (int q = 0; q < LRPT; ++q)
    if (lr[q] >= 0)
      srec[base[lr[q]] + lrk[q]] = make_int2(myrec[q].x & 0xFFFFF, myrec[q].y);  // col only
  __syncthreads();

  // per-wave: 8 rows, register accumulate from LDS-sorted records
  for (int j = 0; j < 8; ++j) {
    int lrow = wid * 8 + j;
    int r = b * 64 + lrow;
    if (r >= N) break;
    int i = base[lrow], end = i + cnt[lrow];
    float a0 = 0.f, a1 = 0.f;
    for (; i + 8 <= end; i += 8) {
      unsigned int u[8];
      float v[8];
#pragma unroll
      for (int q = 0; q < 8; ++q) {
        int2 e = srec[i + q];
        int col = __builtin_amdgcn_readfirstlane(e.x);
        u[q] = hu[(size_t)col * 64 + lane];
        v[q] = __int_as_float(e.y);
      }
#pragma unroll
      for (int q = 0; q < 8; ++q) {
        a0 = fmaf(v[q], bf_lo(u[q]), a0);
        a1 = fmaf(v[q], bf_hi(u[q]), a1);
      }
    }
    for (; i + 4 <= end; i += 4) {
      unsigned int u[4];
      float v[4];
#pragma unroll
      for (int q = 0; q < 4; ++q) {
        int2 e = srec[i + q];
        int col = __builtin_amdgcn_readfirstlane(e.x);
        u[q] = hu[(size_t)col * 64 + lane];
        v[q] = __int_as_float(e.y);
      }
#pragma unroll
      for (int q = 0; q < 4; ++q) {
        a0 = fmaf(v[q], bf_lo(u[q]), a0);
        a1 = fmaf(v[q], bf_hi(u[q]), a1);
      }
    }
    for (; i < end; ++i) {
      int2 e = srec[i];
      int col = __builtin_amdgcn_readfirstlane(e.x);
      unsigned int u = hu[(size_t)col * 64 + lane];
      float v = __int_as_float(e.y);
      a0 = fmaf(v, bf_lo(u), a0);
      a1 = fmaf(v, bf_hi(u), a1);
    }

    // dims: a0 -> lane, a1 -> lane+64 (packed-split h layout)
    float x0 = a0 + b0, x1 = a1 + b1;
    x0 = x0 > 0.f ? x0 : __expf(x0) - 1.f;
    x1 = x1 > 0.f ? x1 : __expf(x1) - 1.f;
    float s = x0 + x1;
#pragma unroll
    for (int d = 1; d < 64; d <<= 1) s += __shfl_xor(s, d);
    float mu = s * (1.f / 128.f);
    float d0 = x0 - mu, d1 = x1 - mu;
    float q2 = d0 * d0 + d1 * d1;
#pragma unroll
    for (int d = 1; d < 64; d <<= 1) q2 += __shfl_xor(q2, d);
    float rstd = rsqrtf(q2 * (1.f / 128.f) + LN_EPS);
    __builtin_nontemporal_store(d0 * rstd * g0 + be0, out + (size_t)r * 128 + lane);
    __builtin_nontemporal_store(d1 * rstd * g1 + be1, out + (size_t)r * 128 + 64 + lane);
  }
}

extern "C" void kernel_launch(void* const* d_in, const int* in_sizes, int n_in,
                              void* d_out, int out_size, void* d_ws, size_t ws_size,
                              hipStream_t stream) {
  const float* feats = (const float*)d_in[0];
  const unsigned int* idx = (const unsigned int*)d_in[1];
  const float* vals = (const float*)d_in[2];
  const float* W = (const float*)d_in[3];
  const float* bias = (const float*)d_in[4];
  const float* gamma = (const float*)d_in[5];
  const float* beta = (const float*)d_in[6];
  float* out = (float*)d_out;
  int N = in_sizes[0] / 128;
  int E = in_sizes[2];
  (void)n_in; (void)out_size; (void)ws_size;

  int NBUK = (N + 63) >> 6;   // 1563 for N=100000 (must be <=2048 for LDS hist)
  int NV = NBUK * 8;          // per-(bucket,xcd) slots
  int mean = (E + NV - 1) / NV;                 // ~128
  int sig = (int)ceilf(sqrtf((float)mean));     // Poisson sigma
  int CAP = ((mean + 8 * sig + 15) / 16) * 16;  // mean + 8 sigma
  if (8 * CAP > SCAPMAX) CAP = SCAPMAX / 8;     // LDS capacity clamp

  char* ws = (char*)d_ws;
  size_t off = 0;
  auto alloc = [&](size_t bytes) {
    char* p = ws + off;
    off += (bytes + 255) & ~(size_t)255;
    return p;
  };
  unsigned int* hu = (unsigned int*)alloc((size_t)N * 64 * 4);  // 25.6MB
  int* scnt = (int*)alloc((size_t)NV * 64);                     // padded counters, 0.8MB
  int2* brec = (int2*)alloc((size_t)NV * CAP * 8);              // ~22.4MB slots

  hipMemsetAsync(scnt, 0, (size_t)NV * 64, stream);

  int SB = (E + 16383) / 16384;  // scatter blocks (16384 edges each)
  int GEMMB = (N + 127) / 128;   // gemm blocks
  k_build<<<SB + GEMMB, 512, 0, stream>>>(idx, vals, feats, W, E, N, CAP, SB, scnt, brec, hu);
  k_spmmL<<<NBUK, 512, 0, stream>>>(hu, scnt, CAP, brec, bias, gamma, beta, out, N);
}